// Round 2
// baseline (82.100 us; speedup 1.0000x reference)
//
#include <hip/hip_runtime.h>
#include <math.h>

#define BIG 1e30f

// QAM-16 gray-coded points, normalized by 1/sqrt(10).
// real: sign=(i>>3)&1, mag=(i>>1)&1 -> +-{1,3}/sqrt(10)
// imag: sign=(i>>2)&1, mag=(i>>0)&1
__device__ __forceinline__ constexpr float QR(int i) {
    return ((((i >> 3) & 1) ? -1.0f : 1.0f) * ((((i >> 1) & 1) ? 3.0f : 1.0f)) *
            0.31622776601683794f);
}
__device__ __forceinline__ constexpr float QI(int i) {
    return ((((i >> 2) & 1) ? -1.0f : 1.0f) * (((i & 1) ? 3.0f : 1.0f)) *
            0.31622776601683794f);
}

// One block per batch. Phase 1: wave 0 does a cooperative 64-lane complex
// Cholesky (lane (i,k) owns element (i,k)) + forward solve of 4 RHS
// (y, h0, h1, h2) -> whitened x columns in LDS. Phase 1b: 9 threads compute
// G = hw^H hw and z = yw^H hw into s_w. Phase 2: 256 threads sweep the 4096
// candidates (thread = (i0,i1), unrolled i2) and reduce bitwise mins to LLRs.
// yn term omitted: constant per batch, cancels in min0-min1.
__global__ __launch_bounds__(256, 1) void mld_fused(
    const float* __restrict__ y_re, const float* __restrict__ y_im,
    const float* __restrict__ h_re, const float* __restrict__ h_im,
    const float* __restrict__ s_re, const float* __restrict__ s_im,
    float* __restrict__ out) {
    int b = blockIdx.x;
    int tid = threadIdx.x;

    __shared__ float s_xr[4][8], s_xi[4][8];  // [c][i]: c=0 yw, c=1..3 hw cols
    __shared__ float s_w[16];                 // g00,g11,g22,g01ri,g02ri,g12ri,z0ri,z1ri,z2ri
    __shared__ float s_tmin[256];
    __shared__ float s_r[32];
    __shared__ float s_m2[32];

    // ---------------- Phase 1: cooperative Cholesky + solves (wave 0) ----------------
    if (tid < 64) {
        int ii = tid >> 3, kk = tid & 7;  // lane owns matrix element (ii, kk)
        float ar = s_re[b * 64 + tid];    // coalesced: 64 lanes read 256B contiguous
        float ai = s_im[b * 64 + tid];
        float br = 0.0f, bi = 0.0f;       // RHS column kk (kk<4): 0=y, 1..3=h cols
        if (kk == 0) {
            br = y_re[b * 8 + ii];
            bi = y_im[b * 8 + ii];
        } else if (kk < 4) {
            br = h_re[b * 24 + ii * 3 + (kk - 1)];
            bi = h_im[b * 24 + ii * 3 + (kk - 1)];
        }

        // Right-looking complex Cholesky (lower). After step j:
        //   column j scaled to L[:,j]; trailing submatrix A[i][k] -= L[i][j]*conj(L[k][j])
#pragma unroll
        for (int j = 0; j < 8; ++j) {
            float djr = __shfl(ar, j * 9, 64);  // A[j][j] (real)
            float dinv = 1.0f / sqrtf(djr);
            if (kk == j && ii >= j) { ar *= dinv; ai *= dinv; }  // incl. diag -> sqrt
            float Lijr = __shfl(ar, ii * 8 + j, 64), Liji = __shfl(ai, ii * 8 + j, 64);
            float Lkjr = __shfl(ar, kk * 8 + j, 64), Lkji = __shfl(ai, kk * 8 + j, 64);
            if (kk > j && ii >= kk) {
                ar -= Lijr * Lkjr + Liji * Lkji;  // -= L[i][j]*conj(L[k][j])
                ai -= Liji * Lkjr - Lijr * Lkji;
            }
        }

        // Forward substitution L x = rhs for 4 columns simultaneously.
#pragma unroll
        for (int k = 0; k < 8; ++k) {
            float dk = __shfl(ar, k * 9, 64);  // L[k][k]
            float dinvk = 1.0f / dk;
            if (ii == k) { br *= dinvk; bi *= dinvk; }  // finalize x[k][c]
            float xkr = __shfl(br, k * 8 + kk, 64), xki = __shfl(bi, k * 8 + kk, 64);
            float Likr = __shfl(ar, ii * 8 + k, 64), Liki = __shfl(ai, ii * 8 + k, 64);
            if (ii > k) {
                br -= Likr * xkr - Liki * xki;  // -= L[i][k]*x[k]
                bi -= Likr * xki + Liki * xkr;
            }
        }
        if (kk < 4) { s_xr[kk][ii] = br; s_xi[kk][ii] = bi; }
    }
    __syncthreads();

    // ---------------- Phase 1b: G (3x3 herm) and z (3) -> s_w ----------------
    if (tid < 9) {
        // pairs (a,c): t0..2 diag |hw_c|^2; t3..5 g01,g02,g12; t6..8 z0,z1,z2
        int a = (int)((0x000211321ull >> (tid * 4)) & 15ull);
        int c = (int)((0x321332321ull >> (tid * 4)) & 15ull);
        float sr = 0.0f, si = 0.0f;
#pragma unroll
        for (int m = 0; m < 8; ++m) {
            float xar = s_xr[a][m], xai = s_xi[a][m];
            float xbr = s_xr[c][m], xbi = s_xi[c][m];
            sr += xar * xbr + xai * xbi;  // conj(xa)*xb
            si += xar * xbi - xai * xbr;
        }
        if (tid < 3) {
            s_w[tid] = sr;
        } else {
            int base = 3 + (tid - 3) * 2;
            s_w[base] = sr;
            s_w[base + 1] = si;
        }
    }
    __syncthreads();

    // ---------------- Phase 2: candidate sweep + bitwise min reduction ----------------
    float g00 = s_w[0], g11 = s_w[1], g22 = s_w[2];
    float g01r = s_w[3], g01i = s_w[4], g02r = s_w[5], g02i = s_w[6];
    float g12r = s_w[7], g12i = s_w[8];
    float z0r = s_w[9], z0i = s_w[10], z1r = s_w[11], z1i = s_w[12];
    float z2r = s_w[13], z2i = s_w[14];

    int i0 = tid >> 4, i1 = tid & 15;
    float p0r = QR(i0), p0i = QI(i0);
    float p1r = QR(i1), p1i = QI(i1);
    float n0 = p0r * p0r + p0i * p0i;
    float n1 = p1r * p1r + p1i * p1i;

    float a0 = g00 * n0 - 2.0f * (z0r * p0r - z0i * p0i);
    float a1 = g11 * n1 - 2.0f * (z1r * p1r - z1i * p1i);
    float crr = p0r * p1r + p0i * p1i;  // conj(p0)*p1
    float cri = p0r * p1i - p0i * p1r;
    float base = a0 + a1 + 2.0f * (g01r * crr - g01i * cri);
    float w0r = g02r * p0r + g02i * p0i;  // g02*conj(p0)
    float w0i = g02i * p0r - g02r * p0i;
    float w1r = g12r * p1r + g12i * p1i;  // g12*conj(p1)
    float w1i = g12i * p1r - g12r * p1i;
    float cr = 2.0f * (w0r + w1r - z2r);
    float ci = -2.0f * (w0i + w1i - z2i);

    float m2[8];  // sym-2 bit n, value v -> m2[n*2+v]
#pragma unroll
    for (int j = 0; j < 8; ++j) m2[j] = BIG;
#pragma unroll
    for (int i2 = 0; i2 < 16; ++i2) {
        float pr = QR(i2), pi = QI(i2);
        float d = base + g22 * (pr * pr + pi * pi) + cr * pr + ci * pi;
        m2[0 + ((i2 >> 3) & 1)] = fminf(m2[0 + ((i2 >> 3) & 1)], d);
        m2[2 + ((i2 >> 2) & 1)] = fminf(m2[2 + ((i2 >> 2) & 1)], d);
        m2[4 + ((i2 >> 1) & 1)] = fminf(m2[4 + ((i2 >> 1) & 1)], d);
        m2[6 + (i2 & 1)]        = fminf(m2[6 + (i2 & 1)], d);
    }
    float tmin = fminf(m2[0], m2[1]);  // min over all i2 for this (i0,i1)

    s_tmin[tid] = tmin;

    // wave-level min reduction of the 8 sym-2 accumulators
#pragma unroll
    for (int j = 0; j < 8; ++j) {
        float v = m2[j];
#pragma unroll
        for (int mask = 1; mask < 64; mask <<= 1) v = fminf(v, __shfl_xor(v, mask, 64));
        m2[j] = v;
    }
    int wave = tid >> 6, lane = tid & 63;
    if (lane == 0) {
#pragma unroll
        for (int j = 0; j < 8; ++j) s_m2[wave * 8 + j] = m2[j];
    }
    __syncthreads();

    if (tid < 16) {
        float m = BIG;
#pragma unroll
        for (int j = 0; j < 16; ++j) m = fminf(m, s_tmin[tid * 16 + j]);
        s_r[tid] = m;  // min over i1 for i0=tid
    } else if (tid < 32) {
        int i1x = tid - 16;
        float m = BIG;
#pragma unroll
        for (int j = 0; j < 16; ++j) m = fminf(m, s_tmin[j * 16 + i1x]);
        s_r[16 + i1x] = m;  // min over i0 for i1=i1x
    }
    __syncthreads();

    if (tid < 12) {
        int k = tid >> 2, n = tid & 3, sh = 3 - n;
        float m0 = BIG, m1 = BIG;
        if (k < 2) {
            const float* r = s_r + k * 16;
#pragma unroll
            for (int j = 0; j < 16; ++j) {
                float v = r[j];
                if ((j >> sh) & 1) m1 = fminf(m1, v);
                else m0 = fminf(m0, v);
            }
        } else {
#pragma unroll
            for (int wv = 0; wv < 4; ++wv) {
                m0 = fminf(m0, s_m2[wv * 8 + n * 2 + 0]);
                m1 = fminf(m1, s_m2[wv * 8 + n * 2 + 1]);
            }
        }
        out[b * 12 + tid] = m0 - m1;  // llr = min0 - min1
    }
}

extern "C" void kernel_launch(void* const* d_in, const int* in_sizes, int n_in,
                              void* d_out, int out_size, void* d_ws, size_t ws_size,
                              hipStream_t stream) {
    const float* y_re = (const float*)d_in[0];
    const float* y_im = (const float*)d_in[1];
    const float* h_re = (const float*)d_in[2];
    const float* h_im = (const float*)d_in[3];
    const float* s_re = (const float*)d_in[4];
    const float* s_im = (const float*)d_in[5];
    int B = in_sizes[0] / 8;  // M = 8

    mld_fused<<<dim3(B), dim3(256), 0, stream>>>(y_re, y_im, h_re, h_im, s_re, s_im,
                                                 (float*)d_out);
}

// Round 3
// 77.132 us; speedup vs baseline: 1.0644x; 1.0644x over previous
//
#include <hip/hip_runtime.h>
#include <math.h>

#define BIG 1e30f
#define RT10 0.31622776601683794f

// QAM-16 gray-coded points, normalized by 1/sqrt(10).
// real: sign=(i>>3)&1, mag=(i>>1)&1 -> +-{1,3}/sqrt(10)
// imag: sign=(i>>2)&1, mag=(i>>0)&1
__device__ __forceinline__ constexpr float QR(int i) {
    return ((((i >> 3) & 1) ? -1.0f : 1.0f) * ((((i >> 1) & 1) ? 3.0f : 1.0f)) * RT10);
}
__device__ __forceinline__ constexpr float QI(int i) {
    return ((((i >> 2) & 1) ? -1.0f : 1.0f) * (((i & 1) ? 3.0f : 1.0f)) * RT10);
}

// One WAVE per batch (4 batches per 256-thread block). Phase 1: 64-lane
// cooperative complex Cholesky + forward solve of 4 RHS (verified in R2).
// Phase 2: lane = (a<<4)|i1 owns i0 in {a, a+4, a+8, a+12} (q loop) x 16 i2.
// All bit-class min reductions are wave-local: 12 butterfly channels
// (8 sym2-bit + 4 sym0-highbit), shuffle trees for sym0 low bits, one
// 16-float LDS pass for sym1 bits. yn term omitted (cancels in min0-min1).
__global__ __launch_bounds__(256) void mld_wave(
    const float* __restrict__ y_re, const float* __restrict__ y_im,
    const float* __restrict__ h_re, const float* __restrict__ h_im,
    const float* __restrict__ s_re, const float* __restrict__ s_im,
    float* __restrict__ out, int B) {
    int tid = threadIdx.x;
    int w = tid >> 6, lane = tid & 63;
    int b = blockIdx.x * 4 + w;
    bool live = (b < B);
    if (!live) b = B - 1;  // clamp: duplicate compute, stores suppressed

    __shared__ float s_xr[4][4][8], s_xi[4][4][8];  // [wave][col][row]
    __shared__ float s_w[4][16];                    // G (3 diag + 3 cplx), z (3 cplx)
    __shared__ float s16[4][16];                    // per-i1 mins

    // ---------------- Phase 1: cooperative Cholesky + solves (all 64 lanes) ----------------
    {
        int ii = lane >> 3, kk = lane & 7;  // lane owns matrix element (ii, kk)
        float ar = s_re[b * 64 + lane];     // coalesced 256B per wave
        float ai = s_im[b * 64 + lane];
        float br = 0.0f, bi = 0.0f;         // RHS column kk (kk<4): 0=y, 1..3=h cols
        if (kk == 0) {
            br = y_re[b * 8 + ii];
            bi = y_im[b * 8 + ii];
        } else if (kk < 4) {
            br = h_re[b * 24 + ii * 3 + (kk - 1)];
            bi = h_im[b * 24 + ii * 3 + (kk - 1)];
        }

        // Right-looking complex Cholesky (lower).
#pragma unroll
        for (int j = 0; j < 8; ++j) {
            float djr = __shfl(ar, j * 9, 64);  // A[j][j] (real)
            float dinv = 1.0f / sqrtf(djr);
            if (kk == j && ii >= j) { ar *= dinv; ai *= dinv; }
            float Lijr = __shfl(ar, ii * 8 + j, 64), Liji = __shfl(ai, ii * 8 + j, 64);
            float Lkjr = __shfl(ar, kk * 8 + j, 64), Lkji = __shfl(ai, kk * 8 + j, 64);
            if (kk > j && ii >= kk) {
                ar -= Lijr * Lkjr + Liji * Lkji;  // -= L[i][j]*conj(L[k][j])
                ai -= Liji * Lkjr - Lijr * Lkji;
            }
        }
        // Forward substitution L x = rhs, 4 columns at once.
#pragma unroll
        for (int k = 0; k < 8; ++k) {
            float dk = __shfl(ar, k * 9, 64);
            float dinvk = 1.0f / dk;
            if (ii == k) { br *= dinvk; bi *= dinvk; }
            float xkr = __shfl(br, k * 8 + kk, 64), xki = __shfl(bi, k * 8 + kk, 64);
            float Likr = __shfl(ar, ii * 8 + k, 64), Liki = __shfl(ai, ii * 8 + k, 64);
            if (ii > k) {
                br -= Likr * xkr - Liki * xki;
                bi -= Likr * xki + Liki * xkr;
            }
        }
        if (kk < 4) { s_xr[w][kk][ii] = br; s_xi[w][kk][ii] = bi; }
    }
    __syncthreads();

    // ---------------- Phase 1b: G (3x3 herm) and z (3) -> s_w ----------------
    if (lane < 9) {
        // pairs (pa,pc): lanes 0..2 diag |hw_c|^2; 3..5 g01,g02,g12; 6..8 z0,z1,z2
        int pa = (int)((0x000211321ull >> (lane * 4)) & 15ull);
        int pc = (int)((0x321332321ull >> (lane * 4)) & 15ull);
        float sr = 0.0f, si = 0.0f;
#pragma unroll
        for (int m = 0; m < 8; ++m) {
            float xar = s_xr[w][pa][m], xai = s_xi[w][pa][m];
            float xbr = s_xr[w][pc][m], xbi = s_xi[w][pc][m];
            sr += xar * xbr + xai * xbi;  // conj(xa)*xb
            si += xar * xbi - xai * xbr;
        }
        if (lane < 3) {
            s_w[w][lane] = sr;
        } else {
            int base2 = 3 + (lane - 3) * 2;
            s_w[w][base2] = sr;
            s_w[w][base2 + 1] = si;
        }
    }
    __syncthreads();

    // ---------------- Phase 2: candidate sweep (4 pairs/lane x 16 i2) ----------------
    const float* ww = s_w[w];
    float g00 = ww[0], g11 = ww[1], g22 = ww[2];
    float g01r = ww[3], g01i = ww[4], g02r = ww[5], g02i = ww[6];
    float g12r = ww[7], g12i = ww[8];
    float z0r = ww[9], z0i = ww[10], z1r = ww[11], z1i = ww[12];
    float z2r = ww[13], z2i = ww[14];

    int a = lane >> 4, i1 = lane & 15;
    float p1r = QR(i1), p1i = QI(i1);
    float n1 = p1r * p1r + p1i * p1i;
    float a1c = g11 * n1 - 2.0f * (z1r * p1r - z1i * p1i);
    float w1r = g12r * p1r + g12i * p1i;  // g12*conj(p1)
    float w1i = g12i * p1r - g12r * p1i;
    float mr0 = (a & 2) ? 3.0f * RT10 : RT10;  // |Re p0|
    float mi0 = (a & 1) ? 3.0f * RT10 : RT10;  // |Im p0|
    float n0 = mr0 * mr0 + mi0 * mi0;
    float g00n0 = g00 * n0;

    float ch[12];  // 0..7: sym2 bit n val v -> ch[n*2+v]; 8..11: sym0 bit3/bit2 classes
#pragma unroll
    for (int j = 0; j < 12; ++j) ch[j] = BIG;
    float u[4];
#pragma unroll
    for (int q = 0; q < 4; ++q) {
        // i0 = a | (q<<2): bit3=q>>1, bit2=q&1 (signs), bit1=a>>1, bit0=a&1 (mags)
        float p0r = (q & 2) ? -mr0 : mr0;
        float p0i = (q & 1) ? -mi0 : mi0;
        float a0c = g00n0 - 2.0f * (z0r * p0r - z0i * p0i);
        float crr = p0r * p1r + p0i * p1i;  // conj(p0)*p1
        float cri = p0r * p1i - p0i * p1r;
        float base = a0c + a1c + 2.0f * (g01r * crr - g01i * cri);
        float w0r = g02r * p0r + g02i * p0i;  // g02*conj(p0)
        float w0i = g02i * p0r - g02r * p0i;
        float cr = 2.0f * (w0r + w1r - z2r);
        float ci = -2.0f * (w0i + w1i - z2i);
        float bA = fmaf(g22, 0.2f, base);  // |p2|^2 in {0.2, 1.0, 1.8}
        float bB = fmaf(g22, 1.0f, base);
        float bC = fmaf(g22, 1.8f, base);
        float pmin = BIG;
#pragma unroll
        for (int i2 = 0; i2 < 16; ++i2) {
            int cls = ((i2 >> 1) & 1) + (i2 & 1);  // compile-time
            float bX = (cls == 0) ? bA : (cls == 1 ? bB : bC);
            float d = fmaf(QI(i2), ci, fmaf(QR(i2), cr, bX));
            pmin = fminf(pmin, d);
            ch[0 + ((i2 >> 3) & 1)] = fminf(ch[0 + ((i2 >> 3) & 1)], d);
            ch[2 + ((i2 >> 2) & 1)] = fminf(ch[2 + ((i2 >> 2) & 1)], d);
            ch[4 + ((i2 >> 1) & 1)] = fminf(ch[4 + ((i2 >> 1) & 1)], d);
            ch[6 + (i2 & 1)]        = fminf(ch[6 + (i2 & 1)], d);
        }
        u[q] = pmin;
    }
    // sym0 high-bit classes (register dim q): bit3 = q>>1, bit2 = q&1
    ch[8] = fminf(u[0], u[1]);   // i0 bit3 = 0
    ch[9] = fminf(u[2], u[3]);   // i0 bit3 = 1
    ch[10] = fminf(u[0], u[2]);  // i0 bit2 = 0
    ch[11] = fminf(u[1], u[3]);  // i0 bit2 = 1

    // full-wave butterfly min of all 12 channels
#pragma unroll
    for (int j = 0; j < 12; ++j) {
        float v = ch[j];
#pragma unroll
        for (int mask = 1; mask < 64; mask <<= 1) v = fminf(v, __shfl_xor(v, mask, 64));
        ch[j] = v;
    }

    float t1 = fminf(fminf(u[0], u[1]), fminf(u[2], u[3]));  // min over q,i2 per (a,i1)
    float r0 = t1;  // -> min over i1 (lane bits 0..3), per a
#pragma unroll
    for (int mask = 1; mask <= 8; mask <<= 1) r0 = fminf(r0, __shfl_xor(r0, mask, 64));
    float r1 = fminf(t1, __shfl_xor(t1, 16, 64));  // -> min over a (lane bits 4,5), per i1
    r1 = fminf(r1, __shfl_xor(r1, 32, 64));
    if (lane < 16) s16[w][lane] = r1;

    // sym0 bit1 (= lane bit5) and bit0 (= lane bit4) classes from r0
    float zv = fminf(r0, __shfl_xor(r0, 16, 64));   // grouped by bit5
    float llr2 = zv - __shfl_xor(zv, 32, 64);       // valid at lanes with bit5=0
    float yv = fminf(r0, __shfl_xor(r0, 32, 64));   // grouped by bit4
    float llr3 = yv - __shfl_xor(yv, 16, 64);       // valid at lanes with bit4=0
    __syncthreads();  // s16 visibility

    // ---------------- Outputs: out[b*12 + k*4 + n], bit = (i_k >> (3-n)) & 1 ----------------
    if (live) {
        float* ob = out + b * 12;
        if (lane == 0) {
            ob[0] = ch[8] - ch[9];    // sym0 n=0 (bit3)
            ob[1] = ch[10] - ch[11];  // sym0 n=1 (bit2)
            ob[2] = llr2;             // sym0 n=2 (bit1)  [lane0: bit5=0 -> class0 resident]
            ob[3] = llr3;             // sym0 n=3 (bit0)  [lane0: bit4=0]
        } else if (lane >= 4 && lane < 8) {
            int k = 3 - (lane - 4);   // sym1 bit index
            float m0 = BIG, m1 = BIG;
#pragma unroll
            for (int j = 0; j < 16; ++j) {
                float v = s16[w][j];  // broadcast reads
                if ((j >> k) & 1) m1 = fminf(m1, v);
                else m0 = fminf(m0, v);
            }
            ob[lane] = m0 - m1;
        } else if (lane >= 8 && lane < 12) {
            int n = lane - 8;         // sym2 bits from butterflied channels
            ob[lane] = ch[n * 2] - ch[n * 2 + 1];
        }
    }
}

extern "C" void kernel_launch(void* const* d_in, const int* in_sizes, int n_in,
                              void* d_out, int out_size, void* d_ws, size_t ws_size,
                              hipStream_t stream) {
    const float* y_re = (const float*)d_in[0];
    const float* y_im = (const float*)d_in[1];
    const float* h_re = (const float*)d_in[2];
    const float* h_im = (const float*)d_in[3];
    const float* s_re = (const float*)d_in[4];
    const float* s_im = (const float*)d_in[5];
    int B = in_sizes[0] / 8;  // M = 8

    mld_wave<<<dim3((B + 3) / 4), dim3(256), 0, stream>>>(y_re, y_im, h_re, h_im,
                                                          s_re, s_im, (float*)d_out, B);
}